// Round 7
// baseline (317.158 us; speedup 1.0000x reference)
//
#include <hip/hip_runtime.h>

#define B_ 8192
#define D_ 512
#define M_ 1000
#define H_ 8
#define LOG2E 1.4426950408889634f

typedef unsigned short u16;
typedef __attribute__((ext_vector_type(8))) short bf16x8;
typedef __attribute__((ext_vector_type(4))) float f32x4;

__device__ __forceinline__ float bf2f(u16 u) {
    union { unsigned u; float f; } c; c.u = ((unsigned)u) << 16; return c.f;
}
__device__ __forceinline__ u16 f2bf(float f) {
    union { float f; unsigned u; } c; c.f = f;
    unsigned r = (c.u + 0x7fffu + ((c.u >> 16) & 1u)) >> 16;
    return (u16)r;
}
__device__ __forceinline__ u16 f2bf_fast(float f) {
    union { float f; unsigned u; } c; c.f = f;
    return (u16)((c.u + 0x8000u) >> 16);
}
__device__ __forceinline__ float wave_sum(float v) {
#pragma unroll
    for (int off = 32; off > 0; off >>= 1) v += __shfl_xor(v, off);
    return v;
}

// ---------------------------------------------------------------------------
// bf16 MFMA GEMM core, 3 K-segments, BK=128 (32 MFMA per barrier).
// C = epi(cscale*A@W^T + bias*bscale). BM=BN=64, 4 waves each 32x32.
// LDS rows are 128 u16 (256B) in 16 chunks of 16B, XOR-swizzled by (row&15)
// -> fragment b128 reads are 2-way (free); staging stays lane-contiguous.
// VTOUT: cols >= 512 written transposed to VT[(col-512)*1024+row], zero-padded.
// ---------------------------------------------------------------------------
template<bool RELU, bool WF32, bool VTOUT>
__device__ __forceinline__ void gemm_core(
    const u16* __restrict__ A0, const u16* __restrict__ A1,
    const u16* __restrict__ A2, int lda0, int lda1, int lda2,
    const u16* __restrict__ W0, const u16* __restrict__ W1,
    const u16* __restrict__ W2, int ldw0, int ldw1, int ldw2,
    int kb1, int kb2,
    const float* __restrict__ bias, float bscale, float cscale,
    float* __restrict__ Cf, u16* __restrict__ Cb, u16* __restrict__ VT,
    int M, int N, int K, int ldc)
{
    const int m0 = blockIdx.y * 64, n0 = blockIdx.x * 64;
    if (m0 >= M || n0 >= N) return;
    __shared__ u16 As[64 * 128];
    __shared__ u16 Bs[64 * 128];
    const int t = threadIdx.x, w = t >> 6, l = t & 63;
    const int wm = (w >> 1) * 32, wn = (w & 1) * 32;
    const int li = l & 15, quad = l >> 4;

    f32x4 acc[2][2];
#pragma unroll
    for (int i = 0; i < 2; ++i)
#pragma unroll
        for (int j = 0; j < 2; ++j) acc[i][j] = (f32x4){0.f, 0.f, 0.f, 0.f};

    for (int k0 = 0; k0 < K; k0 += 128) {
        const u16* Ab; const u16* Wb; int ldab, ldwb, ko;
        if (k0 < kb1)      { Ab = A0; ldab = lda0; Wb = W0; ldwb = ldw0; ko = k0; }
        else if (k0 < kb2) { Ab = A1; ldab = lda1; Wb = W1; ldwb = ldw1; ko = k0 - kb1; }
        else               { Ab = A2; ldab = lda2; Wb = W2; ldwb = ldw2; ko = k0 - kb2; }
#pragma unroll
        for (int i = 0; i < 4; ++i) {
            const int f = i * 256 + t;          // 0..1023
            const int row = f >> 4;             // 0..63
            const int sl = f & 15;
            const int ck = sl ^ (row & 15);
            int ga = m0 + row; ga = ga < M ? ga : M - 1;
            __builtin_amdgcn_global_load_lds(
                (const __attribute__((address_space(1))) void*)(Ab + (size_t)ga * ldab + ko + ck * 8),
                (__attribute__((address_space(3))) void*)(As + f * 8),
                16, 0, 0);
        }
#pragma unroll
        for (int i = 0; i < 4; ++i) {
            const int f = i * 256 + t;
            const int row = f >> 4;
            const int sl = f & 15;
            const int ck = sl ^ (row & 15);
            int gb = n0 + row; gb = gb < N ? gb : N - 1;
            __builtin_amdgcn_global_load_lds(
                (const __attribute__((address_space(1))) void*)(Wb + (size_t)gb * ldwb + ko + ck * 8),
                (__attribute__((address_space(3))) void*)(Bs + f * 8),
                16, 0, 0);
        }
        __syncthreads();
#pragma unroll
        for (int ks = 0; ks < 4; ++ks) {
            const int ch = ks * 4 + quad;
            bf16x8 af[2], bfr[2];
#pragma unroll
            for (int mt = 0; mt < 2; ++mt) {
                const int r = wm + mt * 16 + li;
                af[mt] = *(const bf16x8*)(As + r * 128 + ((ch ^ (r & 15)) * 8));
            }
#pragma unroll
            for (int nt = 0; nt < 2; ++nt) {
                const int r = wn + nt * 16 + li;
                bfr[nt] = *(const bf16x8*)(Bs + r * 128 + ((ch ^ (r & 15)) * 8));
            }
#pragma unroll
            for (int mt = 0; mt < 2; ++mt)
#pragma unroll
                for (int nt = 0; nt < 2; ++nt)
                    acc[mt][nt] = __builtin_amdgcn_mfma_f32_16x16x32_bf16(
                        af[mt], bfr[nt], acc[mt][nt], 0, 0, 0);
        }
        __syncthreads();
    }

    float bv[2];
#pragma unroll
    for (int nt = 0; nt < 2; ++nt) bv[nt] = bias[n0 + wn + nt * 16 + li] * bscale;
#pragma unroll
    for (int mt = 0; mt < 2; ++mt) {
        const int row0 = m0 + wm + mt * 16 + quad * 4;
#pragma unroll
        for (int nt = 0; nt < 2; ++nt) {
            const int col = n0 + wn + nt * 16 + li;
            if (VTOUT && col >= 512) {
                ushort4 pk;
                u16 pv[4];
#pragma unroll
                for (int r = 0; r < 4; ++r) {
                    float v = acc[mt][nt][r] * cscale + bv[nt];
                    pv[r] = (row0 + r < M_) ? f2bf(v) : (u16)0;
                }
                pk.x = pv[0]; pk.y = pv[1]; pk.z = pv[2]; pk.w = pv[3];
                *(ushort4*)(VT + (size_t)(col - 512) * 1024 + row0) = pk;
            } else {
#pragma unroll
                for (int r = 0; r < 4; ++r) {
                    const int row = row0 + r;
                    if (row >= M) continue;
                    float v = acc[mt][nt][r] * cscale + bv[nt];
                    if (RELU) v = fmaxf(v, 0.f);
                    Cb[(size_t)row * ldc + col] = f2bf(v);
                    if (WF32) Cf[(size_t)row * ldc + col] = v;
                }
            }
        }
    }
}

template<bool RELU, bool WF32>
__launch_bounds__(256)
__global__ void mgemm(const u16* __restrict__ A0, const u16* __restrict__ A1,
                      const u16* __restrict__ A2, int lda0, int lda1, int lda2,
                      const u16* __restrict__ W0, const u16* __restrict__ W1,
                      const u16* __restrict__ W2, int ldw0, int ldw1, int ldw2,
                      int kb1, int kb2,
                      const float* __restrict__ bias, float bscale, float cscale,
                      float* __restrict__ Cf, u16* __restrict__ Cb,
                      int M, int N, int K, int ldc)
{
    gemm_core<RELU, WF32, false>(A0, A1, A2, lda0, lda1, lda2,
                                 W0, W1, W2, ldw0, ldw1, ldw2, kb1, kb2,
                                 bias, bscale, cscale, Cf, Cb, nullptr, M, N, K, ldc);
}

// three weight-fold GEMMs in one dispatch (z selects config)
__launch_bounds__(256)
__global__ void foldgemm(const u16* __restrict__ w_q, const u16* __restrict__ w_tr1,
                         const u16* __restrict__ w_e2t, const u16* __restrict__ w_wot,
                         const float* __restrict__ zb,
                         u16* __restrict__ w_qe, u16* __restrict__ w_ae,
                         u16* __restrict__ w_co)
{
    const int z = blockIdx.z;
    if (z == 0)
        gemm_core<false, false, false>(w_q, w_q, w_q, 512, 512, 512,
            w_e2t, w_e2t, w_e2t, 512, 512, 512, 512, 512,
            zb, 0.f, 1.0f, nullptr, w_qe, nullptr, 512, 512, 512, 512);
    else if (z == 1)
        gemm_core<false, false, false>(w_tr1, w_tr1, w_tr1, 576, 576, 576,
            w_e2t, w_e2t, w_e2t, 512, 512, 512, 512, 512,
            zb, 0.f, 0.7f, nullptr, w_ae, nullptr, 512, 512, 512, 512);
    else
        gemm_core<false, false, false>(w_tr1, w_tr1, w_tr1, 576, 576, 576,
            w_wot, w_wot, w_wot, 512, 512, 512, 512, 512,
            zb, 0.f, 0.3f, nullptr, w_co, nullptr, 512, 512, 512, 512);
}

// q-projection (z=0) + fused K|V projection with direct-VT write (z=1)
__launch_bounds__(256)
__global__ void qkvgemm(const u16* __restrict__ hn, const u16* __restrict__ w_qe,
                        const float* __restrict__ bqe, u16* __restrict__ qbuf,
                        const u16* __restrict__ wmem_bf, const u16* __restrict__ w_k,
                        const float* __restrict__ bkv, u16* __restrict__ KVbuf,
                        u16* __restrict__ VTb)
{
    if (blockIdx.z == 0)
        gemm_core<false, false, false>(hn, hn, hn, 512, 512, 512,
            w_qe, w_qe, w_qe, 512, 512, 512, 512, 512,
            bqe, 1.f, 1.f, nullptr, qbuf, nullptr, B_, 512, 512, 512);
    else
        gemm_core<false, false, true>(wmem_bf, wmem_bf, wmem_bf, 512, 512, 512,
            w_k, w_k, w_k, 512, 512, 512, 512, 512,
            bkv, 1.f, 1.f, nullptr, KVbuf, VTb, 1024, 1024, 512, 1024);
}

// ---------------------------------------------------------------------------
// Fused flash attention, no-max softmax (q pre-scaled log2e/8), split-K x2.
// 32-key chunks + launch_bounds(256,4): <=128 regs/wave -> 4 blocks/CU.
// Block = 128 q x 1 head x 1 key-half (4 waves x 32 q-rows). Partial O (bf16)
// and l (f32, via MFMA-ones) to workspace; exact combine (no-max => sums).
// P swizzle: slot = (chunk ^ (row&3)) | ((row>>2&1)<<2) -> b128 reads 2-way.
// ---------------------------------------------------------------------------
__launch_bounds__(256, 4)
__global__ void attn_kernel(const u16* __restrict__ Q, const u16* __restrict__ KV,
                            const u16* __restrict__ VT, u16* __restrict__ Ob,
                            float* __restrict__ Lb)
{
    __shared__ u16 P[4 * 2048];
    const int t = threadIdx.x, w = t >> 6, l = t & 63;
    const int h = blockIdx.y;
    const int qblk = blockIdx.x & 63, kpart = blockIdx.x >> 6;
    const int q0 = qblk * 128 + w * 32;
    u16* Pw = P + w * 2048;
    const int li = l & 15, quad = l >> 4;

    bf16x8 aq[2][2];
#pragma unroll
    for (int mt = 0; mt < 2; ++mt)
#pragma unroll
        for (int ks = 0; ks < 2; ++ks) {
            const int row = q0 + mt * 16 + li;
            aq[mt][ks] = *(const bf16x8*)(Q + (size_t)row * 512 + h * 64 + ks * 32 + quad * 8);
        }

    bf16x8 ones;
#pragma unroll
    for (int i = 0; i < 8; ++i) ones[i] = (short)0x3F80;

    f32x4 oacc[2][4];
    f32x4 lacc[2];
#pragma unroll
    for (int mt = 0; mt < 2; ++mt) {
        lacc[mt] = (f32x4){0.f, 0.f, 0.f, 0.f};
#pragma unroll
        for (int nt = 0; nt < 4; ++nt) oacc[mt][nt] = (f32x4){0.f, 0.f, 0.f, 0.f};
    }

    const int kbeg = kpart * 512, kend = kbeg + 512;
    for (int kc = kbeg; kc < kend; kc += 32) {
        f32x4 s[2][2];
#pragma unroll
        for (int mt = 0; mt < 2; ++mt)
#pragma unroll
            for (int nt = 0; nt < 2; ++nt) s[mt][nt] = (f32x4){0.f, 0.f, 0.f, 0.f};
#pragma unroll
        for (int ks = 0; ks < 2; ++ks) {
            bf16x8 bk[2];
#pragma unroll
            for (int nt = 0; nt < 2; ++nt) {
                const int key = kc + nt * 16 + li;
                bk[nt] = *(const bf16x8*)(KV + (size_t)key * 1024 + h * 64 + ks * 32 + quad * 8);
            }
#pragma unroll
            for (int mt = 0; mt < 2; ++mt)
#pragma unroll
                for (int nt = 0; nt < 2; ++nt)
                    s[mt][nt] = __builtin_amdgcn_mfma_f32_16x16x32_bf16(
                        aq[mt][ks], bk[nt], s[mt][nt], 0, 0, 0);
        }
        if (kc == 992) {   // keys 992..1023: only valid < 1000
#pragma unroll
            for (int nt = 0; nt < 2; ++nt) {
                const bool val = (992 + nt * 16 + li) < M_;
#pragma unroll
                for (int mt = 0; mt < 2; ++mt)
#pragma unroll
                    for (int r = 0; r < 4; ++r)
                        if (!val) s[mt][nt][r] = -3.0e38f;
            }
        }
#pragma unroll
        for (int mt = 0; mt < 2; ++mt)
#pragma unroll
            for (int nt = 0; nt < 2; ++nt) {
                const int col = nt * 16 + li;
                const int c = col >> 3;
#pragma unroll
                for (int r = 0; r < 4; ++r) {
                    const float p = exp2f(s[mt][nt][r]);   // log2e folded into q
                    const int row = mt * 16 + quad * 4 + r;
                    const int slot = (c ^ (row & 3)) | (((row >> 2) & 1) << 2);
                    Pw[row * 64 + slot * 8 + (col & 7)] = f2bf_fast(p);
                }
            }
        // PV + l (single K=32 step consumes the whole chunk)
        bf16x8 ap[2];
#pragma unroll
        for (int mt = 0; mt < 2; ++mt) {
            const int row = mt * 16 + li;
            const int slot = (quad ^ (row & 3)) | (((row >> 2) & 1) << 2);
            ap[mt] = *(const bf16x8*)(Pw + row * 64 + slot * 8);
        }
#pragma unroll
        for (int mt = 0; mt < 2; ++mt)
            lacc[mt] = __builtin_amdgcn_mfma_f32_16x16x32_bf16(
                ap[mt], ones, lacc[mt], 0, 0, 0);
#pragma unroll
        for (int nt = 0; nt < 4; ++nt) {
            const bf16x8 bvv = *(const bf16x8*)(VT + ((size_t)(h * 64 + nt * 16 + li)) * 1024 + kc + quad * 8);
#pragma unroll
            for (int mt = 0; mt < 2; ++mt)
                oacc[mt][nt] = __builtin_amdgcn_mfma_f32_16x16x32_bf16(
                    ap[mt], bvv, oacc[mt][nt], 0, 0, 0);
        }
    }

    u16* Op = Ob + (size_t)kpart * B_ * 512;
    float* Lp = Lb + (size_t)kpart * B_ * 8;
#pragma unroll
    for (int mt = 0; mt < 2; ++mt)
#pragma unroll
        for (int r = 0; r < 4; ++r) {
            const int row = q0 + mt * 16 + quad * 4 + r;
            if (li == 0) Lp[row * 8 + h] = lacc[mt][r];
#pragma unroll
            for (int nt = 0; nt < 4; ++nt)
                Op[(size_t)row * 512 + h * 64 + nt * 16 + li] = f2bf(oacc[mt][nt][r]);
        }
}

// ctx = (O0 + O1) / (l0 + l1), bf16 out. one wave per 512-col row.
__launch_bounds__(256)
__global__ void attn_combine(const u16* __restrict__ Ob, const float* __restrict__ Lb,
                             u16* __restrict__ ctx)
{
    const int row = blockIdx.x * 4 + (threadIdx.x >> 6);
    const int lane = threadIdx.x & 63;
    const int h = lane >> 3;
    const float inv = 1.0f / (Lb[row * 8 + h] + Lb[(size_t)B_ * 8 + row * 8 + h]);
    const u16* p0 = Ob + (size_t)row * 512 + lane * 8;
    const u16* p1 = p0 + (size_t)B_ * 512;
    uint4 a = *(const uint4*)p0;
    uint4 b = *(const uint4*)p1;
    const unsigned aa[4] = {a.x, a.y, a.z, a.w};
    const unsigned bb[4] = {b.x, b.y, b.z, b.w};
    unsigned o[4];
#pragma unroll
    for (int i = 0; i < 4; ++i) {
        const float lo = (bf2f((u16)(aa[i] & 0xffffu)) + bf2f((u16)(bb[i] & 0xffffu))) * inv;
        const float hi = (bf2f((u16)(aa[i] >> 16)) + bf2f((u16)(bb[i] >> 16))) * inv;
        o[i] = (unsigned)f2bf(lo) | ((unsigned)f2bf(hi) << 16);
    }
    *(uint4*)(ctx + (size_t)row * 512 + lane * 8) = make_uint4(o[0], o[1], o[2], o[3]);
}

__launch_bounds__(256)
__global__ void ln_bf(u16* __restrict__ X, const float* __restrict__ g,
                      const float* __restrict__ be, int rows)
{
    const int row = blockIdx.x * 4 + (threadIdx.x >> 6);
    const int lane = threadIdx.x & 63;
    if (row >= rows) return;
    u16* p = X + (size_t)row * 512 + lane * 8;
    uint4 d = *(const uint4*)p;
    const unsigned dd[4] = {d.x, d.y, d.z, d.w};
    float v[8];
#pragma unroll
    for (int i = 0; i < 4; ++i) {
        v[2 * i]     = bf2f((u16)(dd[i] & 0xffffu));
        v[2 * i + 1] = bf2f((u16)(dd[i] >> 16));
    }
    float s = 0.f;
#pragma unroll
    for (int i = 0; i < 8; ++i) s += v[i];
    s = wave_sum(s);
    const float mu = s * (1.0f / 512.0f);
    float vs = 0.f;
#pragma unroll
    for (int i = 0; i < 8; ++i) { v[i] -= mu; vs += v[i] * v[i]; }
    vs = wave_sum(vs);
    const float r = rsqrtf(vs * (1.0f / 512.0f) + 1e-5f);
    const float* gp = g + lane * 8;
    const float* bp = be + lane * 8;
    unsigned o[4];
#pragma unroll
    for (int i = 0; i < 4; ++i) {
        const u16 lo = f2bf(v[2 * i] * r * gp[2 * i] + bp[2 * i]);
        const u16 hi = f2bf(v[2 * i + 1] * r * gp[2 * i + 1] + bp[2 * i + 1]);
        o[i] = (unsigned)lo | ((unsigned)hi << 16);
    }
    *(uint4*)p = make_uint4(o[0], o[1], o[2], o[3]);
}

// one-dispatch prep: weight converts (0-6), transposes (7-8), activation
// converts (9-11), bias folds (12-13)
__launch_bounds__(256)
__global__ void prep_all(const float* enc_w1, const float* wk_f, const float* wv_f,
                         const float* tr_w2, const float* q_w1, const float* wq,
                         const float* tr_w1, const float* enc_w2, const float* wo,
                         const float* obs, const float* wmem, const float* ego,
                         const float* bk, const float* bvv, const float* bq,
                         const float* enc_b2, const float* trb1, const float* bo,
                         u16* w_enc1, u16* w_k, u16* w_v, u16* w_tr2, u16* w_qh,
                         u16* w_q, u16* w_tr1, u16* w_e2t, u16* w_wot,
                         u16* obs_bf, u16* wmem_bf, u16* ego128,
                         float* bkv, float* bqe, float* btr)
{
    __shared__ float tl[64][65];
    const int seg = blockIdx.y;
    const int t = threadIdx.x;
    const int bx = blockIdx.x;

    if (seg <= 5) {   // plain f32 -> bf16 weight converts
        const float* s; u16* d; int n; float sc = 1.0f;
        switch (seg) {
            case 0: s = enc_w1; d = w_enc1; n = 262144; break;
            case 1: s = wk_f;   d = w_k;    n = 262144; break;
            case 2: s = wv_f;   d = w_v;    n = 262144; break;
            case 3: s = tr_w2;  d = w_tr2;  n = 262144; break;
            case 4: s = q_w1;   d = w_qh;   n = 65536;  break;
            default: s = wq;    d = w_q;    n = 262144; sc = 0.125f * LOG2E; break;
        }
        const int i0 = (bx * 256 + t) * 4;
        if (i0 + 3 < n) {
            const float4 v = *(const float4*)(s + i0);
            ushort4 o;
            o.x = f2bf(v.x * sc); o.y = f2bf(v.y * sc);
            o.z = f2bf(v.z * sc); o.w = f2bf(v.w * sc);
            *(ushort4*)(d + i0) = o;
        }
    } else if (seg == 6) {   // tr_w1 [512,528] -> [512,576] zero-pad
#pragma unroll
        for (int k = 0; k < 4; ++k) {
            const int i = (bx * 256 + t) * 4 + k;
            if (i < 294912) {
                const int r = i / 576, c = i - r * 576;
                w_tr1[i] = (c < 528) ? f2bf(tr_w1[r * 528 + c]) : (u16)0;
            }
        }
    } else if (seg <= 8) {   // transpose enc_w2 / wo -> bf16
        if (bx >= 64) return;
        const float* S = (seg == 7) ? enc_w2 : wo;
        u16* D = (seg == 7) ? w_e2t : w_wot;
        const int r0 = (bx >> 3) * 64, c0 = (bx & 7) * 64;
#pragma unroll
        for (int i = 0; i < 16; ++i) {
            const int idx = t + i * 256;
            tl[idx >> 6][idx & 63] = S[(size_t)(r0 + (idx >> 6)) * 512 + c0 + (idx & 63)];
        }
        __syncthreads();
#pragma unroll
        for (int i = 0; i < 16; ++i) {
            const int idx = t + i * 256;
            const int c = idx >> 6, r = idx & 63;
            D[(size_t)(c0 + c) * 512 + r0 + r] = f2bf(tl[r][c]);
        }
    } else if (seg == 9) {   // obs -> bf16
        const int nth = gridDim.x * 256;
        for (int i = bx * 256 + t; i < B_ * 512 / 4; i += nth) {
            const float4 v = ((const float4*)obs)[i];
            ushort4 o;
            o.x = f2bf(v.x); o.y = f2bf(v.y); o.z = f2bf(v.z); o.w = f2bf(v.w);
            ((ushort4*)obs_bf)[i] = o;
        }
    } else if (seg == 10) {  // wmem -> bf16
        const int nth = gridDim.x * 256;
        for (int i = bx * 256 + t; i < M_ * 512 / 4; i += nth) {
            const float4 v = ((const float4*)wmem)[i];
            ushort4 o;
            o.x = f2bf(v.x); o.y = f2bf(v.y); o.z = f2bf(v.z); o.w = f2bf(v.w);
            ((ushort4*)wmem_bf)[i] = o;
        }
    } else if (seg == 11) {  // ego128 (zero-padded to 128 cols) + fused kv bias
        const int nth = gridDim.x * 256;
        for (int i = bx * 256 + t; i < B_ * 128; i += nth) {
            const int b = i >> 7, j = i & 127;
            ego128[(size_t)b * 128 + j] = (j < 16) ? f2bf(ego[b * 16 + j]) : (u16)0;
        }
        const int tid = bx * 256 + t;
        if (tid < 1024) bkv[tid] = (tid < 512) ? bk[tid] : bvv[tid - 512];
    } else {   // bias folds
        if (bx >= 128) return;
        const int i = bx * 4 + (t >> 6);
        const int lane = t & 63;
        float s = 0.f;
        if (seg == 12) {
            const float* wr = wq + (size_t)i * 512 + lane * 8;
#pragma unroll
            for (int j = 0; j < 8; ++j) s += wr[j] * enc_b2[lane * 8 + j];
            s = wave_sum(s);
            if (lane == 0) bqe[i] = 0.125f * LOG2E * (bq[i] + s);
        } else {
            const float* wr = tr_w1 + (size_t)i * 528 + lane * 8;
#pragma unroll
            for (int j = 0; j < 8; ++j)
                s += wr[j] * (0.7f * enc_b2[lane * 8 + j] + 0.3f * bo[lane * 8 + j]);
            s = wave_sum(s);
            if (lane == 0) btr[i] = trb1[i] + s;
        }
    }
}

__global__ void quality_bf(const u16* __restrict__ qh, const float* __restrict__ w2,
                           const float* __restrict__ b2, float* __restrict__ outq,
                           int rows)
{
    const int row = blockIdx.x * 4 + (threadIdx.x >> 6);
    const int lane = threadIdx.x & 63;
    if (row >= rows) return;
    const u16* p = qh + (size_t)row * 128;
    float s = bf2f(p[lane]) * w2[lane] + bf2f(p[64 + lane]) * w2[64 + lane];
    s = wave_sum(s);
    if (lane == 0) outq[row] = 1.0f / (1.0f + expf(-(s + b2[0])));
}

__global__ void compact_kernel(const float* __restrict__ q,
                               int* __restrict__ list, int* __restrict__ cnt)
{
    __shared__ int wtot[16];
    __shared__ int sbase;
    const int t = threadIdx.x, w = t >> 6, lane = t & 63;
    if (t == 0) sbase = 0;
    __syncthreads();
    for (int c = 0; c < B_; c += 1024) {
        const int idx = c + t;
        const bool pred = (q[idx] > 0.7f);
        const unsigned long long bal = __ballot(pred);
        const int prefix = __popcll(bal & ((1ull << lane) - 1ull));
        if (lane == 0) wtot[w] = __popcll(bal);
        __syncthreads();
        int woff = 0;
        for (int i = 0; i < w; ++i) woff += wtot[i];
        if (pred) list[sbase + woff + prefix] = idx;
        __syncthreads();
        if (t == 0) {
            int tot = 0;
            for (int i = 0; i < 16; ++i) tot += wtot[i];
            sbase += tot;
        }
        __syncthreads();
    }
    if (t == 0) *cnt = sbase;
}

__global__ void update_memory_kernel(const float* __restrict__ mem,
                                     const float* __restrict__ ns,
                                     const int* __restrict__ upd,
                                     const int* __restrict__ list,
                                     const int* __restrict__ cnt,
                                     float* __restrict__ outmem)
{
    const int m = blockIdx.x;
    const int t = threadIdx.x;
    const int c4 = t * 4;
    float4 r = *(const float4*)(mem + (size_t)m * D_ + c4);
    const int n = *cnt;
    for (int i = 0; i < n; ++i) {
        const int b = list[i];
        if (upd[b] == m) {
            const float4 s = *(const float4*)(ns + (size_t)b * D_ + c4);
            r.x = 0.9f * r.x + 0.1f * s.x;
            r.y = 0.9f * r.y + 0.1f * s.y;
            r.z = 0.9f * r.z + 0.1f * s.z;
            r.w = 0.9f * r.w + 0.1f * s.w;
        }
    }
    *(float4*)(outmem + (size_t)m * D_ + c4) = r;
}

extern "C" void kernel_launch(void* const* d_in, const int* in_sizes, int n_in,
                              void* d_out, int out_size, void* d_ws, size_t ws_size,
                              hipStream_t stream)
{
    const float* obs    = (const float*)d_in[0];
    const float* ego    = (const float*)d_in[1];
    const float* wmem   = (const float*)d_in[2];
    const float* enc_w1 = (const float*)d_in[3];
    const float* enc_b1 = (const float*)d_in[4];
    const float* enc_g  = (const float*)d_in[5];
    const float* enc_be = (const float*)d_in[6];
    const float* enc_w2 = (const float*)d_in[7];
    const float* enc_b2 = (const float*)d_in[8];
    const float* wq = (const float*)d_in[9];
    const float* bq = (const float*)d_in[10];
    const float* wk_f = (const float*)d_in[11];
    const float* bk = (const float*)d_in[12];
    const float* wv_f = (const float*)d_in[13];
    const float* bvv = (const float*)d_in[14];
    const float* wo = (const float*)d_in[15];
    const float* bo = (const float*)d_in[16];
    const float* tr_w1 = (const float*)d_in[17];
    const float* tr_b1 = (const float*)d_in[18];
    const float* tr_g  = (const float*)d_in[19];
    const float* tr_be = (const float*)d_in[20];
    const float* tr_w2 = (const float*)d_in[21];
    const float* tr_b2 = (const float*)d_in[22];
    const float* q_w1 = (const float*)d_in[23];
    const float* q_b1 = (const float*)d_in[24];
    const float* q_w2 = (const float*)d_in[25];
    const float* q_b2 = (const float*)d_in[26];
    const int*   upd  = (const int*)d_in[27];

    float* out_ns  = (float*)d_out;
    float* out_q   = out_ns + (size_t)B_ * D_;
    float* out_mem = out_q + B_;

    u16* ws = (u16*)d_ws;
    size_t o = 0;
    u16* obs_bf  = ws + o; o += (size_t)B_ * 512;
    u16* wmem_bf = ws + o; o += (size_t)M_ * 512;
    u16* w_enc1  = ws + o; o += 262144;
    u16* w_k     = ws + o; o += 262144;   // contiguous with w_v -> fused KV weight
    u16* w_v     = ws + o; o += 262144;
    u16* w_tr2   = ws + o; o += 262144;
    u16* w_qh    = ws + o; o += 65536;
    u16* w_q     = ws + o; o += 262144;
    u16* w_tr1   = ws + o; o += (size_t)512 * 576;
    u16* w_e2t   = ws + o; o += 262144;
    u16* w_wot   = ws + o; o += 262144;
    u16* w_qe    = ws + o; o += 262144;
    u16* w_ae    = ws + o; o += 262144;
    u16* w_co    = ws + o; o += 262144;
    u16* hbuf    = ws + o; o += (size_t)B_ * 512;
    u16* qbuf    = ws + o; o += (size_t)B_ * 512;
    u16* KVbuf   = ws + o; o += (size_t)1024 * 1024;
    u16* VTb     = ws + o; o += (size_t)512 * 1024;
    u16* ctx     = ws + o; o += (size_t)B_ * 512;
    u16* h2b     = ws + o; o += (size_t)B_ * 512;
    u16* nsbf    = ws + o; o += (size_t)B_ * 512;
    u16* qhb     = ws + o; o += (size_t)B_ * 128;
    u16* ego128  = ws + o; o += (size_t)B_ * 128;
    u16* Obuf    = ws + o; o += (size_t)2 * B_ * 512;   // split-K O partials
    float* Lbuf  = (float*)(ws + o); o += (size_t)2 * B_ * 8 * 2;
    float* bkv   = (float*)(ws + o); o += 2048;
    float* bqe   = (float*)(ws + o); o += 1024;
    float* btr   = (float*)(ws + o); o += 1024;
    int* list    = (int*)(ws + o);
    int* cnt     = list + B_;

    const dim3 blk(256);

    // one-dispatch prep (converts, transposes, bias folds)
    prep_all<<<dim3(576, 14), blk, 0, stream>>>(
        enc_w1, wk_f, wv_f, tr_w2, q_w1, wq, tr_w1, enc_w2, wo,
        obs, wmem, ego, bk, bvv, bq, enc_b2, tr_b1, bo,
        w_enc1, w_k, w_v, w_tr2, w_qh, w_q, w_tr1, w_e2t, w_wot,
        obs_bf, wmem_bf, ego128, bkv, bqe, btr);

    // weight folds in one dispatch
    foldgemm<<<dim3(8, 8, 3), blk, 0, stream>>>(w_q, w_tr1, w_e2t, w_wot, bkv,
                                                w_qe, w_ae, w_co);

    // encoder layer 1 + LN -> hn
    mgemm<true, false><<<dim3(8, 128), blk, 0, stream>>>(
        obs_bf, obs_bf, obs_bf, 512, 512, 512, w_enc1, w_enc1, w_enc1, 512, 512, 512,
        512, 512, enc_b1, 1.f, 1.f, nullptr, hbuf, B_, 512, 512, 512);
    ln_bf<<<dim3(2048), blk, 0, stream>>>(hbuf, enc_g, enc_be, B_);

    // q-projection + fused K|V projection (V written directly transposed to VT)
    qkvgemm<<<dim3(16, 128, 2), blk, 0, stream>>>(
        hbuf, w_qe, bqe, qbuf, wmem_bf, w_k, bkv, KVbuf, VTb);

    // fused attention, split-K x2 -> partials; exact combine
    attn_kernel<<<dim3(128, 8), blk, 0, stream>>>(qbuf, KVbuf, VTb, Obuf, Lbuf);
    attn_combine<<<dim3(2048), blk, 0, stream>>>(Obuf, Lbuf, ctx);

    // folded transition layer 1: h2 = relu([hn|ctx|ego128] @ [0.7Wae|0.3Wco|trw1b]^T + btr)
    mgemm<true, false><<<dim3(8, 128), blk, 0, stream>>>(
        hbuf, ctx, ego128, 512, 512, 128, w_ae, w_co, w_tr1 + 512, 512, 512, 576,
        512, 1024, btr, 1.f, 1.f, nullptr, h2b, B_, 512, 1152, 512);
    ln_bf<<<dim3(2048), blk, 0, stream>>>(h2b, tr_g, tr_be, B_);

    // next_state (f32 out + bf16 for downstream)
    mgemm<false, true><<<dim3(8, 128), blk, 0, stream>>>(
        h2b, h2b, h2b, 512, 512, 512, w_tr2, w_tr2, w_tr2, 512, 512, 512,
        512, 512, tr_b2, 1.f, 1.f, out_ns, nsbf, B_, 512, 512, 512);

    // quality head
    mgemm<true, false><<<dim3(2, 128), blk, 0, stream>>>(
        nsbf, nsbf, nsbf, 512, 512, 512, w_qh, w_qh, w_qh, 512, 512, 512,
        512, 512, q_b1, 1.f, 1.f, nullptr, qhb, B_, 128, 512, 128);
    quality_bf<<<dim3(2048), blk, 0, stream>>>(qhb, q_w2, q_b2, out_q, B_);

    // memory bank scatter-EMA
    compact_kernel<<<dim3(1), dim3(1024), 0, stream>>>(out_q, list, cnt);
    update_memory_kernel<<<dim3(M_), dim3(128), 0, stream>>>(
        wmem, out_ns, upd, list, cnt, out_mem);
}

// Round 8
// 278.976 us; speedup vs baseline: 1.1369x; 1.1369x over previous
//
#include <hip/hip_runtime.h>

#define B_ 8192
#define D_ 512
#define M_ 1000
#define H_ 8
#define LOG2E 1.4426950408889634f

typedef unsigned short u16;
typedef __attribute__((ext_vector_type(8))) short bf16x8;
typedef __attribute__((ext_vector_type(4))) float f32x4;

__device__ __forceinline__ float bf2f(u16 u) {
    union { unsigned u; float f; } c; c.u = ((unsigned)u) << 16; return c.f;
}
__device__ __forceinline__ u16 f2bf(float f) {
    union { float f; unsigned u; } c; c.f = f;
    unsigned r = (c.u + 0x7fffu + ((c.u >> 16) & 1u)) >> 16;
    return (u16)r;
}
__device__ __forceinline__ u16 f2bf_fast(float f) {
    union { float f; unsigned u; } c; c.f = f;
    return (u16)((c.u + 0x8000u) >> 16);
}
__device__ __forceinline__ float wave_sum(float v) {
#pragma unroll
    for (int off = 32; off > 0; off >>= 1) v += __shfl_xor(v, off);
    return v;
}

// ---------------------------------------------------------------------------
// bf16 MFMA GEMM core (R6 config: BK=64), 3 K-segments.
// C = epi(cscale*A@W^T + bias*bscale). BM=BN=64, 4 waves each 32x32.
// VTOUT: cols >= 512 written transposed to VT[(col-512)*1024+row], zero-padded.
// ---------------------------------------------------------------------------
template<bool RELU, bool WF32, bool VTOUT>
__device__ __forceinline__ void gemm_core(
    const u16* __restrict__ A0, const u16* __restrict__ A1,
    const u16* __restrict__ A2, int lda0, int lda1, int lda2,
    const u16* __restrict__ W0, const u16* __restrict__ W1,
    const u16* __restrict__ W2, int ldw0, int ldw1, int ldw2,
    int kb1, int kb2,
    const float* __restrict__ bias, float bscale, float cscale,
    float* __restrict__ Cf, u16* __restrict__ Cb, u16* __restrict__ VT,
    int M, int N, int K, int ldc)
{
    const int m0 = blockIdx.y * 64, n0 = blockIdx.x * 64;
    if (m0 >= M || n0 >= N) return;
    __shared__ u16 As[64 * 64];
    __shared__ u16 Bs[64 * 64];
    const int t = threadIdx.x, w = t >> 6, l = t & 63;
    const int wm = (w >> 1) * 32, wn = (w & 1) * 32;
    const int li = l & 15, quad = l >> 4;

    f32x4 acc[2][2];
#pragma unroll
    for (int i = 0; i < 2; ++i)
#pragma unroll
        for (int j = 0; j < 2; ++j) acc[i][j] = (f32x4){0.f, 0.f, 0.f, 0.f};

    for (int k0 = 0; k0 < K; k0 += 64) {
        const u16* Ab; const u16* Wb; int ldab, ldwb, ko;
        if (k0 < kb1)      { Ab = A0; ldab = lda0; Wb = W0; ldwb = ldw0; ko = k0; }
        else if (k0 < kb2) { Ab = A1; ldab = lda1; Wb = W1; ldwb = ldw1; ko = k0 - kb1; }
        else               { Ab = A2; ldab = lda2; Wb = W2; ldwb = ldw2; ko = k0 - kb2; }
#pragma unroll
        for (int i = 0; i < 2; ++i) {
            const int rl = w * 16 + i * 8 + (l >> 3);
            const int ck = (l & 7) ^ (rl & 7);
            int ga = m0 + rl; ga = ga < M ? ga : M - 1;
            __builtin_amdgcn_global_load_lds(
                (const __attribute__((address_space(1))) void*)(Ab + (size_t)ga * ldab + ko + ck * 8),
                (__attribute__((address_space(3))) void*)(As + (w * 16 + i * 8) * 64),
                16, 0, 0);
        }
#pragma unroll
        for (int i = 0; i < 2; ++i) {
            const int rl = w * 16 + i * 8 + (l >> 3);
            const int ck = (l & 7) ^ (rl & 7);
            int gb = n0 + rl; gb = gb < N ? gb : N - 1;
            __builtin_amdgcn_global_load_lds(
                (const __attribute__((address_space(1))) void*)(Wb + (size_t)gb * ldwb + ko + ck * 8),
                (__attribute__((address_space(3))) void*)(Bs + (w * 16 + i * 8) * 64),
                16, 0, 0);
        }
        __syncthreads();
#pragma unroll
        for (int ks = 0; ks < 2; ++ks) {
            const int ch = ks * 4 + quad;
            bf16x8 af[2], bfr[2];
#pragma unroll
            for (int mt = 0; mt < 2; ++mt) {
                const int r = wm + mt * 16 + li;
                af[mt] = *(const bf16x8*)(As + r * 64 + ((ch ^ (r & 7)) * 8));
            }
#pragma unroll
            for (int nt = 0; nt < 2; ++nt) {
                const int r = wn + nt * 16 + li;
                bfr[nt] = *(const bf16x8*)(Bs + r * 64 + ((ch ^ (r & 7)) * 8));
            }
#pragma unroll
            for (int mt = 0; mt < 2; ++mt)
#pragma unroll
                for (int nt = 0; nt < 2; ++nt)
                    acc[mt][nt] = __builtin_amdgcn_mfma_f32_16x16x32_bf16(
                        af[mt], bfr[nt], acc[mt][nt], 0, 0, 0);
        }
        __syncthreads();
    }

    float bv[2];
#pragma unroll
    for (int nt = 0; nt < 2; ++nt) bv[nt] = bias[n0 + wn + nt * 16 + li] * bscale;
#pragma unroll
    for (int mt = 0; mt < 2; ++mt) {
        const int row0 = m0 + wm + mt * 16 + quad * 4;
#pragma unroll
        for (int nt = 0; nt < 2; ++nt) {
            const int col = n0 + wn + nt * 16 + li;
            if (VTOUT && col >= 512) {
                ushort4 pk;
                u16 pv[4];
#pragma unroll
                for (int r = 0; r < 4; ++r) {
                    float v = acc[mt][nt][r] * cscale + bv[nt];
                    pv[r] = (row0 + r < M_) ? f2bf(v) : (u16)0;
                }
                pk.x = pv[0]; pk.y = pv[1]; pk.z = pv[2]; pk.w = pv[3];
                *(ushort4*)(VT + (size_t)(col - 512) * 1024 + row0) = pk;
            } else {
#pragma unroll
                for (int r = 0; r < 4; ++r) {
                    const int row = row0 + r;
                    if (row >= M) continue;
                    float v = acc[mt][nt][r] * cscale + bv[nt];
                    if (RELU) v = fmaxf(v, 0.f);
                    Cb[(size_t)row * ldc + col] = f2bf(v);
                    if (WF32) Cf[(size_t)row * ldc + col] = v;
                }
            }
        }
    }
}

template<bool RELU, bool WF32>
__launch_bounds__(256)
__global__ void mgemm(const u16* __restrict__ A0, const u16* __restrict__ A1,
                      const u16* __restrict__ A2, int lda0, int lda1, int lda2,
                      const u16* __restrict__ W0, const u16* __restrict__ W1,
                      const u16* __restrict__ W2, int ldw0, int ldw1, int ldw2,
                      int kb1, int kb2,
                      const float* __restrict__ bias, float bscale, float cscale,
                      float* __restrict__ Cf, u16* __restrict__ Cb,
                      int M, int N, int K, int ldc)
{
    gemm_core<RELU, WF32, false>(A0, A1, A2, lda0, lda1, lda2,
                                 W0, W1, W2, ldw0, ldw1, ldw2, kb1, kb2,
                                 bias, bscale, cscale, Cf, Cb, nullptr, M, N, K, ldc);
}

// three weight-fold GEMMs in one dispatch (z selects config)
__launch_bounds__(256)
__global__ void foldgemm(const u16* __restrict__ w_q, const u16* __restrict__ w_tr1,
                         const u16* __restrict__ w_e2t, const u16* __restrict__ w_wot,
                         const float* __restrict__ zb,
                         u16* __restrict__ w_qe, u16* __restrict__ w_ae,
                         u16* __restrict__ w_co)
{
    const int z = blockIdx.z;
    if (z == 0)
        gemm_core<false, false, false>(w_q, w_q, w_q, 512, 512, 512,
            w_e2t, w_e2t, w_e2t, 512, 512, 512, 512, 512,
            zb, 0.f, 1.0f, nullptr, w_qe, nullptr, 512, 512, 512, 512);
    else if (z == 1)
        gemm_core<false, false, false>(w_tr1, w_tr1, w_tr1, 576, 576, 576,
            w_e2t, w_e2t, w_e2t, 512, 512, 512, 512, 512,
            zb, 0.f, 0.7f, nullptr, w_ae, nullptr, 512, 512, 512, 512);
    else
        gemm_core<false, false, false>(w_tr1, w_tr1, w_tr1, 576, 576, 576,
            w_wot, w_wot, w_wot, 512, 512, 512, 512, 512,
            zb, 0.f, 0.3f, nullptr, w_co, nullptr, 512, 512, 512, 512);
}

// q-projection (z=0) + fused K|V projection with direct-VT write (z=1)
__launch_bounds__(256)
__global__ void qkvgemm(const u16* __restrict__ hn, const u16* __restrict__ w_qe,
                        const float* __restrict__ bqe, u16* __restrict__ qbuf,
                        const u16* __restrict__ wmem_bf, const u16* __restrict__ w_k,
                        const float* __restrict__ bkv, u16* __restrict__ KVbuf,
                        u16* __restrict__ VTb)
{
    if (blockIdx.z == 0)
        gemm_core<false, false, false>(hn, hn, hn, 512, 512, 512,
            w_qe, w_qe, w_qe, 512, 512, 512, 512, 512,
            bqe, 1.f, 1.f, nullptr, qbuf, nullptr, B_, 512, 512, 512);
    else
        gemm_core<false, false, true>(wmem_bf, wmem_bf, wmem_bf, 512, 512, 512,
            w_k, w_k, w_k, 512, 512, 512, 512, 512,
            bkv, 1.f, 1.f, nullptr, KVbuf, VTb, 1024, 1024, 512, 1024);
}

// ---------------------------------------------------------------------------
// Fused flash attention, no-max softmax (q pre-scaled log2e/8), split-K x2.
// K/V chunks staged through LDS (global_load_lds w=16, double-buffered, one
// barrier per 64-key chunk) -> each K/V line fetched ONCE per block instead of
// once per wave (kills the L1/TA redundancy that pinned R3/R6/R7 at ~69 us).
// Block = 128 q x 1 head x 1 key-half. Partials to workspace; exact combine.
// ---------------------------------------------------------------------------
__launch_bounds__(256)
__global__ void attn_kernel(const u16* __restrict__ Q, const u16* __restrict__ KV,
                            const u16* __restrict__ VT, u16* __restrict__ Ob,
                            float* __restrict__ Lb)
{
    __shared__ u16 Ks[2][64 * 64];
    __shared__ u16 Vs[2][64 * 64];
    __shared__ u16 P[4 * 2048];
    const int t = threadIdx.x, w = t >> 6, l = t & 63;
    const int h = blockIdx.y;
    const int qblk = blockIdx.x & 63, kpart = blockIdx.x >> 6;
    const int q0 = qblk * 128 + w * 32;
    u16* Pw = P + w * 2048;
    const int li = l & 15, quad = l >> 4;
    const int kbeg = kpart * 512;

    bf16x8 aq[2][2];
#pragma unroll
    for (int mt = 0; mt < 2; ++mt)
#pragma unroll
        for (int ks = 0; ks < 2; ++ks) {
            const int row = q0 + mt * 16 + li;
            aq[mt][ks] = *(const bf16x8*)(Q + (size_t)row * 512 + h * 64 + ks * 32 + quad * 8);
        }

    bf16x8 ones;
#pragma unroll
    for (int i = 0; i < 8; ++i) ones[i] = (short)0x3F80;

    f32x4 oacc[2][4];
    f32x4 lacc[2];
#pragma unroll
    for (int mt = 0; mt < 2; ++mt) {
        lacc[mt] = (f32x4){0.f, 0.f, 0.f, 0.f};
#pragma unroll
        for (int nt = 0; nt < 4; ++nt) oacc[mt][nt] = (f32x4){0.f, 0.f, 0.f, 0.f};
    }

    // stage 64 keys of K (rows = local key, 64 dims) and V (rows = dh, 64 keys)
    auto stage = [&](int kc, int buf) {
#pragma unroll
        for (int i = 0; i < 2; ++i) {
            const int f = i * 256 + t;
            const int r = f >> 3;                  // local key 0..63
            const int ck = (f & 7) ^ (r & 7);
            __builtin_amdgcn_global_load_lds(
                (const __attribute__((address_space(1))) void*)(KV + (size_t)(kc + r) * 1024 + h * 64 + ck * 8),
                (__attribute__((address_space(3))) void*)(&Ks[buf][f * 8]),
                16, 0, 0);
        }
#pragma unroll
        for (int i = 0; i < 2; ++i) {
            const int f = i * 256 + t;
            const int r = f >> 3;                  // dh 0..63
            const int ck = (f & 7) ^ (r & 7);
            __builtin_amdgcn_global_load_lds(
                (const __attribute__((address_space(1))) void*)(VT + (size_t)(h * 64 + r) * 1024 + kc + ck * 8),
                (__attribute__((address_space(3))) void*)(&Vs[buf][f * 8]),
                16, 0, 0);
        }
    };

    stage(kbeg, 0);
    for (int ic = 0; ic < 8; ++ic) {
        const int kc = kbeg + ic * 64;
        __syncthreads();                 // staging for buf ic&1 drained; prev compute done
        if (ic < 7) stage(kc + 64, (ic + 1) & 1);
        const u16* ksb = &Ks[ic & 1][0];
        const u16* vsb = &Vs[ic & 1][0];

        f32x4 s[2][4];
#pragma unroll
        for (int mt = 0; mt < 2; ++mt)
#pragma unroll
            for (int nt = 0; nt < 4; ++nt) s[mt][nt] = (f32x4){0.f, 0.f, 0.f, 0.f};
#pragma unroll
        for (int ks = 0; ks < 2; ++ks) {
            const int ch = ks * 4 + quad;
            bf16x8 bk[4];
#pragma unroll
            for (int nt = 0; nt < 4; ++nt) {
                const int key = nt * 16 + li;
                bk[nt] = *(const bf16x8*)(ksb + key * 64 + ((ch ^ (key & 7)) * 8));
            }
#pragma unroll
            for (int mt = 0; mt < 2; ++mt)
#pragma unroll
                for (int nt = 0; nt < 4; ++nt)
                    s[mt][nt] = __builtin_amdgcn_mfma_f32_16x16x32_bf16(
                        aq[mt][ks], bk[nt], s[mt][nt], 0, 0, 0);
        }
        if (kc == 960) {   // padded keys live only in the final chunk of kpart 1
#pragma unroll
            for (int nt = 0; nt < 4; ++nt) {
                const bool val = (960 + nt * 16 + li) < M_;
#pragma unroll
                for (int mt = 0; mt < 2; ++mt)
#pragma unroll
                    for (int r = 0; r < 4; ++r)
                        if (!val) s[mt][nt][r] = -3.0e38f;
            }
        }
#pragma unroll
        for (int mt = 0; mt < 2; ++mt)
#pragma unroll
            for (int nt = 0; nt < 4; ++nt) {
                const int col = nt * 16 + li;
#pragma unroll
                for (int r = 0; r < 4; ++r) {
                    const float p = exp2f(s[mt][nt][r]);   // log2e folded into q
                    const int rowl = mt * 16 + quad * 4 + r;
                    Pw[rowl * 64 + (((col >> 3) ^ (rowl & 7)) * 8) + (col & 7)] = f2bf_fast(p);
                }
            }
#pragma unroll
        for (int ks = 0; ks < 2; ++ks) {
            const int ch = ks * 4 + quad;
            bf16x8 ap[2];
#pragma unroll
            for (int mt = 0; mt < 2; ++mt) {
                const int rowl = mt * 16 + li;
                ap[mt] = *(const bf16x8*)(Pw + rowl * 64 + ((ch ^ (rowl & 7)) * 8));
            }
#pragma unroll
            for (int mt = 0; mt < 2; ++mt)
                lacc[mt] = __builtin_amdgcn_mfma_f32_16x16x32_bf16(
                    ap[mt], ones, lacc[mt], 0, 0, 0);
#pragma unroll
            for (int nt = 0; nt < 4; ++nt) {
                const int dh = nt * 16 + li;
                const bf16x8 bvv = *(const bf16x8*)(vsb + dh * 64 + ((ch ^ (dh & 7)) * 8));
#pragma unroll
                for (int mt = 0; mt < 2; ++mt)
                    oacc[mt][nt] = __builtin_amdgcn_mfma_f32_16x16x32_bf16(
                        ap[mt], bvv, oacc[mt][nt], 0, 0, 0);
            }
        }
    }

    u16* Op = Ob + (size_t)kpart * B_ * 512;
    float* Lp = Lb + (size_t)kpart * B_ * 8;
#pragma unroll
    for (int mt = 0; mt < 2; ++mt)
#pragma unroll
        for (int r = 0; r < 4; ++r) {
            const int row = q0 + mt * 16 + quad * 4 + r;
            if (li == 0) Lp[row * 8 + h] = lacc[mt][r];
#pragma unroll
            for (int nt = 0; nt < 4; ++nt)
                Op[(size_t)row * 512 + h * 64 + nt * 16 + li] = f2bf(oacc[mt][nt][r]);
        }
}

// ctx = (O0 + O1) / (l0 + l1), bf16 out. one wave per 512-col row.
__launch_bounds__(256)
__global__ void attn_combine(const u16* __restrict__ Ob, const float* __restrict__ Lb,
                             u16* __restrict__ ctx)
{
    const int row = blockIdx.x * 4 + (threadIdx.x >> 6);
    const int lane = threadIdx.x & 63;
    const int h = lane >> 3;
    const float inv = 1.0f / (Lb[row * 8 + h] + Lb[(size_t)B_ * 8 + row * 8 + h]);
    const u16* p0 = Ob + (size_t)row * 512 + lane * 8;
    const u16* p1 = p0 + (size_t)B_ * 512;
    uint4 a = *(const uint4*)p0;
    uint4 b = *(const uint4*)p1;
    const unsigned aa[4] = {a.x, a.y, a.z, a.w};
    const unsigned bb[4] = {b.x, b.y, b.z, b.w};
    unsigned o[4];
#pragma unroll
    for (int i = 0; i < 4; ++i) {
        const float lo = (bf2f((u16)(aa[i] & 0xffffu)) + bf2f((u16)(bb[i] & 0xffffu))) * inv;
        const float hi = (bf2f((u16)(aa[i] >> 16)) + bf2f((u16)(bb[i] >> 16))) * inv;
        o[i] = (unsigned)f2bf(lo) | ((unsigned)f2bf(hi) << 16);
    }
    *(uint4*)(ctx + (size_t)row * 512 + lane * 8) = make_uint4(o[0], o[1], o[2], o[3]);
}

__launch_bounds__(256)
__global__ void ln_bf(u16* __restrict__ X, const float* __restrict__ g,
                      const float* __restrict__ be, int rows)
{
    const int row = blockIdx.x * 4 + (threadIdx.x >> 6);
    const int lane = threadIdx.x & 63;
    if (row >= rows) return;
    u16* p = X + (size_t)row * 512 + lane * 8;
    uint4 d = *(const uint4*)p;
    const unsigned dd[4] = {d.x, d.y, d.z, d.w};
    float v[8];
#pragma unroll
    for (int i = 0; i < 4; ++i) {
        v[2 * i]     = bf2f((u16)(dd[i] & 0xffffu));
        v[2 * i + 1] = bf2f((u16)(dd[i] >> 16));
    }
    float s = 0.f;
#pragma unroll
    for (int i = 0; i < 8; ++i) s += v[i];
    s = wave_sum(s);
    const float mu = s * (1.0f / 512.0f);
    float vs = 0.f;
#pragma unroll
    for (int i = 0; i < 8; ++i) { v[i] -= mu; vs += v[i] * v[i]; }
    vs = wave_sum(vs);
    const float r = rsqrtf(vs * (1.0f / 512.0f) + 1e-5f);
    const float* gp = g + lane * 8;
    const float* bp = be + lane * 8;
    unsigned o[4];
#pragma unroll
    for (int i = 0; i < 4; ++i) {
        const u16 lo = f2bf(v[2 * i] * r * gp[2 * i] + bp[2 * i]);
        const u16 hi = f2bf(v[2 * i + 1] * r * gp[2 * i + 1] + bp[2 * i + 1]);
        o[i] = (unsigned)lo | ((unsigned)hi << 16);
    }
    *(uint4*)p = make_uint4(o[0], o[1], o[2], o[3]);
}

// one-dispatch prep: weight converts (0-6), transposes (7-8), activation
// converts (9-11), bias folds (12-13)
__launch_bounds__(256)
__global__ void prep_all(const float* enc_w1, const float* wk_f, const float* wv_f,
                         const float* tr_w2, const float* q_w1, const float* wq,
                         const float* tr_w1, const float* enc_w2, const float* wo,
                         const float* obs, const float* wmem, const float* ego,
                         const float* bk, const float* bvv, const float* bq,
                         const float* enc_b2, const float* trb1, const float* bo,
                         u16* w_enc1, u16* w_k, u16* w_v, u16* w_tr2, u16* w_qh,
                         u16* w_q, u16* w_tr1, u16* w_e2t, u16* w_wot,
                         u16* obs_bf, u16* wmem_bf, u16* ego64,
                         float* bkv, float* bqe, float* btr)
{
    __shared__ float tl[64][65];
    const int seg = blockIdx.y;
    const int t = threadIdx.x;
    const int bx = blockIdx.x;

    if (seg <= 5) {
        const float* s; u16* d; int n; float sc = 1.0f;
        switch (seg) {
            case 0: s = enc_w1; d = w_enc1; n = 262144; break;
            case 1: s = wk_f;   d = w_k;    n = 262144; break;
            case 2: s = wv_f;   d = w_v;    n = 262144; break;
            case 3: s = tr_w2;  d = w_tr2;  n = 262144; break;
            case 4: s = q_w1;   d = w_qh;   n = 65536;  break;
            default: s = wq;    d = w_q;    n = 262144; sc = 0.125f * LOG2E; break;
        }
        const int i0 = (bx * 256 + t) * 4;
        if (i0 + 3 < n) {
            const float4 v = *(const float4*)(s + i0);
            ushort4 o;
            o.x = f2bf(v.x * sc); o.y = f2bf(v.y * sc);
            o.z = f2bf(v.z * sc); o.w = f2bf(v.w * sc);
            *(ushort4*)(d + i0) = o;
        }
    } else if (seg == 6) {
#pragma unroll
        for (int k = 0; k < 4; ++k) {
            const int i = (bx * 256 + t) * 4 + k;
            if (i < 294912) {
                const int r = i / 576, c = i - r * 576;
                w_tr1[i] = (c < 528) ? f2bf(tr_w1[r * 528 + c]) : (u16)0;
            }
        }
    } else if (seg <= 8) {
        if (bx >= 64) return;
        const float* S = (seg == 7) ? enc_w2 : wo;
        u16* D = (seg == 7) ? w_e2t : w_wot;
        const int r0 = (bx >> 3) * 64, c0 = (bx & 7) * 64;
#pragma unroll
        for (int i = 0; i < 16; ++i) {
            const int idx = t + i * 256;
            tl[idx >> 6][idx & 63] = S[(size_t)(r0 + (idx >> 6)) * 512 + c0 + (idx & 63)];
        }
        __syncthreads();
#pragma unroll
        for (int i = 0; i < 16; ++i) {
            const int idx = t + i * 256;
            const int c = idx >> 6, r = idx & 63;
            D[(size_t)(c0 + c) * 512 + r0 + r] = f2bf(tl[r][c]);
        }
    } else if (seg == 9) {
        const int nth = gridDim.x * 256;
        for (int i = bx * 256 + t; i < B_ * 512 / 4; i += nth) {
            const float4 v = ((const float4*)obs)[i];
            ushort4 o;
            o.x = f2bf(v.x); o.y = f2bf(v.y); o.z = f2bf(v.z); o.w = f2bf(v.w);
            ((ushort4*)obs_bf)[i] = o;
        }
    } else if (seg == 10) {
        const int nth = gridDim.x * 256;
        for (int i = bx * 256 + t; i < M_ * 512 / 4; i += nth) {
            const float4 v = ((const float4*)wmem)[i];
            ushort4 o;
            o.x = f2bf(v.x); o.y = f2bf(v.y); o.z = f2bf(v.z); o.w = f2bf(v.w);
            ((ushort4*)wmem_bf)[i] = o;
        }
    } else if (seg == 11) {
        const int nth = gridDim.x * 256;
        for (int i = bx * 256 + t; i < B_ * 64; i += nth) {
            const int b = i >> 6, j = i & 63;
            ego64[(size_t)b * 64 + j] = (j < 16) ? f2bf(ego[b * 16 + j]) : (u16)0;
        }
        const int tid = bx * 256 + t;
        if (tid < 1024) bkv[tid] = (tid < 512) ? bk[tid] : bvv[tid - 512];
    } else {
        if (bx >= 128) return;
        const int i = bx * 4 + (t >> 6);
        const int lane = t & 63;
        float s = 0.f;
        if (seg == 12) {
            const float* wr = wq + (size_t)i * 512 + lane * 8;
#pragma unroll
            for (int j = 0; j < 8; ++j) s += wr[j] * enc_b2[lane * 8 + j];
            s = wave_sum(s);
            if (lane == 0) bqe[i] = 0.125f * LOG2E * (bq[i] + s);
        } else {
            const float* wr = tr_w1 + (size_t)i * 528 + lane * 8;
#pragma unroll
            for (int j = 0; j < 8; ++j)
                s += wr[j] * (0.7f * enc_b2[lane * 8 + j] + 0.3f * bo[lane * 8 + j]);
            s = wave_sum(s);
            if (lane == 0) btr[i] = trb1[i] + s;
        }
    }
}

__global__ void quality_bf(const u16* __restrict__ qh, const float* __restrict__ w2,
                           const float* __restrict__ b2, float* __restrict__ outq,
                           int rows)
{
    const int row = blockIdx.x * 4 + (threadIdx.x >> 6);
    const int lane = threadIdx.x & 63;
    if (row >= rows) return;
    const u16* p = qh + (size_t)row * 128;
    float s = bf2f(p[lane]) * w2[lane] + bf2f(p[64 + lane]) * w2[64 + lane];
    s = wave_sum(s);
    if (lane == 0) outq[row] = 1.0f / (1.0f + expf(-(s + b2[0])));
}

__global__ void compact_kernel(const float* __restrict__ q,
                               int* __restrict__ list, int* __restrict__ cnt)
{
    __shared__ int wtot[16];
    __shared__ int sbase;
    const int t = threadIdx.x, w = t >> 6, lane = t & 63;
    if (t == 0) sbase = 0;
    __syncthreads();
    for (int c = 0; c < B_; c += 1024) {
        const int idx = c + t;
        const bool pred = (q[idx] > 0.7f);
        const unsigned long long bal = __ballot(pred);
        const int prefix = __popcll(bal & ((1ull << lane) - 1ull));
        if (lane == 0) wtot[w] = __popcll(bal);
        __syncthreads();
        int woff = 0;
        for (int i = 0; i < w; ++i) woff += wtot[i];
        if (pred) list[sbase + woff + prefix] = idx;
        __syncthreads();
        if (t == 0) {
            int tot = 0;
            for (int i = 0; i < 16; ++i) tot += wtot[i];
            sbase += tot;
        }
        __syncthreads();
    }
    if (t == 0) *cnt = sbase;
}

__global__ void update_memory_kernel(const float* __restrict__ mem,
                                     const float* __restrict__ ns,
                                     const int* __restrict__ upd,
                                     const int* __restrict__ list,
                                     const int* __restrict__ cnt,
                                     float* __restrict__ outmem)
{
    const int m = blockIdx.x;
    const int t = threadIdx.x;
    const int c4 = t * 4;
    float4 r = *(const float4*)(mem + (size_t)m * D_ + c4);
    const int n = *cnt;
    for (int i = 0; i < n; ++i) {
        const int b = list[i];
        if (upd[b] == m) {
            const float4 s = *(const float4*)(ns + (size_t)b * D_ + c4);
            r.x = 0.9f * r.x + 0.1f * s.x;
            r.y = 0.9f * r.y + 0.1f * s.y;
            r.z = 0.9f * r.z + 0.1f * s.z;
            r.w = 0.9f * r.w + 0.1f * s.w;
        }
    }
    *(float4*)(outmem + (size_t)m * D_ + c4) = r;
}

extern "C" void kernel_launch(void* const* d_in, const int* in_sizes, int n_in,
                              void* d_out, int out_size, void* d_ws, size_t ws_size,
                              hipStream_t stream)
{
    const float* obs    = (const float*)d_in[0];
    const float* ego    = (const float*)d_in[1];
    const float* wmem   = (const float*)d_in[2];
    const float* enc_w1 = (const float*)d_in[3];
    const float* enc_b1 = (const float*)d_in[4];
    const float* enc_g  = (const float*)d_in[5];
    const float* enc_be = (const float*)d_in[6];
    const float* enc_w2 = (const float*)d_in[7];
    const float* enc_b2 = (const float*)d_in[8];
    const float* wq = (const float*)d_in[9];
    const float* bq = (const float*)d_in[10];
    const float* wk_f = (const float*)d_in[11];
    const float* bk = (const float*)d_in[12];
    const float* wv_f = (const float*)d_in[13];
    const float* bvv = (const float*)d_in[14];
    const float* wo = (const float*)d_in[15];
    const float* bo = (const float*)d_in[16];
    const float* tr_w1 = (const float*)d_in[17];
    const float* tr_b1 = (const float*)d_in[18];
    const float* tr_g  = (const float*)d_in[19];
    const float* tr_be = (const float*)d_in[20];
    const float* tr_w2 = (const float*)d_in[21];
    const float* tr_b2 = (const float*)d_in[22];
    const float* q_w1 = (const float*)d_in[23];
    const float* q_b1 = (const float*)d_in[24];
    const float* q_w2 = (const float*)d_in[25];
    const float* q_b2 = (const float*)d_in[26];
    const int*   upd  = (const int*)d_in[27];

    float* out_ns  = (float*)d_out;
    float* out_q   = out_ns + (size_t)B_ * D_;
    float* out_mem = out_q + B_;

    u16* ws = (u16*)d_ws;
    size_t o = 0;
    u16* obs_bf  = ws + o; o += (size_t)B_ * 512;
    u16* wmem_bf = ws + o; o += (size_t)M_ * 512;
    u16* w_enc1  = ws + o; o += 262144;
    u16* w_k     = ws + o; o += 262144;   // contiguous with w_v -> fused KV weight
    u16* w_v     = ws + o; o += 262144;
    u16* w_tr2   = ws + o; o += 262144;
    u16* w_qh    = ws + o; o += 65536;
    u16* w_q     = ws + o; o += 262144;
    u16* w_tr1   = ws + o; o += (size_t)512 * 576;
    u16* w_e2t   = ws + o; o += 262144;
    u16* w_wot   = ws + o; o += 262144;
    u16* w_qe    = ws + o; o += 262144;
    u16* w_ae    = ws + o; o += 262144;
    u16* w_co    = ws + o; o += 262144;
    u16* hbuf    = ws + o; o += (size_t)B_ * 512;
    u16* qbuf    = ws + o; o += (size_t)B_ * 512;
    u16* KVbuf   = ws + o; o += (size_t)1024 * 1024;
    u16* VTb     = ws + o; o += (size_t)512 * 1024;
    u16* ctx     = ws + o; o += (size_t)B_ * 512;
    u16* h2b     = ws + o; o += (size_t)B_ * 512;
    u16* nsbf    = ws + o; o += (size_t)B_ * 512;
    u16* qhb     = ws + o; o += (size_t)B_ * 128;
    u16* ego64   = ws + o; o += (size_t)B_ * 64;
    u16* Obuf    = ws + o; o += (size_t)2 * B_ * 512;
    float* Lbuf  = (float*)(ws + o); o += (size_t)2 * B_ * 8 * 2;
    float* bkv   = (float*)(ws + o); o += 2048;
    float* bqe   = (float*)(ws + o); o += 1024;
    float* btr   = (float*)(ws + o); o += 1024;
    int* list    = (int*)(ws + o);
    int* cnt     = list + B_;

    const dim3 blk(256);

    prep_all<<<dim3(576, 14), blk, 0, stream>>>(
        enc_w1, wk_f, wv_f, tr_w2, q_w1, wq, tr_w1, enc_w2, wo,
        obs, wmem, ego, bk, bvv, bq, enc_b2, tr_b1, bo,
        w_enc1, w_k, w_v, w_tr2, w_qh, w_q, w_tr1, w_e2t, w_wot,
        obs_bf, wmem_bf, ego64, bkv, bqe, btr);

    foldgemm<<<dim3(8, 8, 3), blk, 0, stream>>>(w_q, w_tr1, w_e2t, w_wot, bkv,
                                                w_qe, w_ae, w_co);

    mgemm<true, false><<<dim3(8, 128), blk, 0, stream>>>(
        obs_bf, obs_bf, obs_bf, 512, 512, 512, w_enc1, w_enc1, w_enc1, 512, 512, 512,
        512, 512, enc_b1, 1.f, 1.f, nullptr, hbuf, B_, 512, 512, 512);
    ln_bf<<<dim3(2048), blk, 0, stream>>>(hbuf, enc_g, enc_be, B_);

    qkvgemm<<<dim3(16, 128, 2), blk, 0, stream>>>(
        hbuf, w_qe, bqe, qbuf, wmem_bf, w_k, bkv, KVbuf, VTb);

    attn_kernel<<<dim3(128, 8), blk, 0, stream>>>(qbuf, KVbuf, VTb, Obuf, Lbuf);
    attn_combine<<<dim3(2048), blk, 0, stream>>>(Obuf, Lbuf, ctx);

    mgemm<true, false><<<dim3(8, 128), blk, 0, stream>>>(
        hbuf, ctx, ego64, 512, 512, 64, w_ae, w_co, w_tr1 + 512, 512, 512, 576,
        512, 1024, btr, 1.f, 1.f, nullptr, h2b, B_, 512, 1088, 512);
    ln_bf<<<dim3(2048), blk, 0, stream>>>(h2b, tr_g, tr_be, B_);

    mgemm<false, true><<<dim3(8, 128), blk, 0, stream>>>(
        h2b, h2b, h2b, 512, 512, 512, w_tr2, w_tr2, w_tr2, 512, 512, 512,
        512, 512, tr_b2, 1.f, 1.f, out_ns, nsbf, B_, 512, 512, 512);

    mgemm<true, false><<<dim3(2, 128), blk, 0, stream>>>(
        nsbf, nsbf, nsbf, 512, 512, 512, w_qh, w_qh, w_qh, 512, 512, 512,
        512, 512, q_b1, 1.f, 1.f, nullptr, qhb, B_, 128, 512, 128);
    quality_bf<<<dim3(2048), blk, 0, stream>>>(qhb, q_w2, q_b2, out_q, B_);

    compact_kernel<<<dim3(1), dim3(1024), 0, stream>>>(out_q, list, cnt);
    update_memory_kernel<<<dim3(M_), dim3(128), 0, stream>>>(
        wmem, out_ns, upd, list, cnt, out_mem);
}